// Round 10
// baseline (218.578 us; speedup 1.0000x reference)
//
#include <hip/hip_runtime.h>
#include <hip/hip_bf16.h>

// LaplaceCostNet — MI355X (gfx950), round 27.
// R26: wave de-phasing HURT (43->53us) — 4th falsified schedule theory.
// Conclusion: mlp is latency-bound at the hard 128-reg/4-wave-per-SIMD wall
// (4 x 128 = full 512-reg file); per-wave critical path is the invariant.
// mlp frozen at R23 form.
// R27: kernel-time audit: ~53-57us of GPU work vs 118 total -> ~60us is
// graph-node overhead (12 nodes, 8 harness resets). R24/R25: merges needing
// cross-block coordination are 10-100x worse than the node they save. The
// prep->mlp merge needs NONE: each mlp block transforms its own staged
// layers from L2-resident Wh (R16 swizzle is per-chunk arithmetic).
// prep_kernel deleted; dispatches 4 -> 3. Stages placed after xform_all
// (acc dead -> only fragv+inn live) + unroll-2 chunk loop to hold VGPR <= 64.
// Numerics bit-identical.
//
// Workspace (bytes):
//   [262144 .. +1MB)     C    fp32
//   [262144+3MB .. +4MB) Vfin fp32

typedef unsigned short ushort_t;
typedef short short8 __attribute__((ext_vector_type(8)));
typedef float floatx16 __attribute__((ext_vector_type(16)));
typedef unsigned int uintx4 __attribute__((ext_vector_type(4)));

#define HH 512
#define WW 512
#define NPIX (HH*WW)

__device__ inline unsigned int pk_bf16(float a, float b) {   // a->low16, b->high16
    __hip_bfloat162 h = __float22bfloat162_rn(float2{a, b});
    return *(unsigned int*)&h;
}

// one layer K-loop from LDS buffer BUF; addresses = inner[ks] + i*8192 (immediates)
template<int BUF>
__device__ __forceinline__ void klayer(const ushort_t* __restrict__ wlds,
                                       const int (&inn)[8],
                                       const uintx4 (&fragv)[8],
                                       floatx16 (&acc)[4]) {
    #pragma unroll
    for (int i = 0; i < 4; ++i) acc[i] = (floatx16)(0.0f);
    #pragma unroll
    for (int ks = 0; ks < 8; ++ks) {
        short8 bf = __builtin_bit_cast(short8, fragv[ks]);
        #pragma unroll
        for (int i = 0; i < 4; ++i) {
            short8 av = *(const short8*)((const char*)wlds + BUF * 32768 + i * 8192 + inn[ks]);
            acc[i] = __builtin_amdgcn_mfma_f32_32x32x16_bf16(av, bf, acc[i], 0, 0, 0);
        }
    }
}

// C -> next B-frags: pure in-lane relu+pack (pi-matched, no shuffles)
__device__ __forceinline__ void xform_all(uintx4 (&fragv)[8], const floatx16 (&acc)[4]) {
    #pragma unroll
    for (int ks = 0; ks < 8; ++ks) {
        const int i = ks >> 1, par = ks & 1;
        fragv[ks][0] = pk_bf16(fmaxf(acc[i][8 * par + 0], 0.0f),
                               fmaxf(acc[i][8 * par + 1], 0.0f));
        fragv[ks][1] = pk_bf16(fmaxf(acc[i][8 * par + 2], 0.0f),
                               fmaxf(acc[i][8 * par + 3], 0.0f));
        fragv[ks][2] = pk_bf16(fmaxf(acc[i][8 * par + 4], 0.0f),
                               fmaxf(acc[i][8 * par + 5], 0.0f));
        fragv[ks][3] = pk_bf16(fmaxf(acc[i][8 * par + 6], 0.0f),
                               fmaxf(acc[i][8 * par + 7], 0.0f));
    }
}

// in-block R16 transform+stage of layer l into buffer buf:
// 2048 chunks (n 0..127, P 0..15); chunk cc = P^(n&15) = 2ks+Hh, pi-permuted
// k slots {base..base+3, base+8..base+11}, base=(ks>>1)*32+(ks&1)*16+Hq*4.
// Wh is L2-resident (256 KB). unroll 2 keeps load temps bounded (VGPR wall).
__device__ __forceinline__ void stage_xform(ushort_t* wlds, int buf,
                                            const float* __restrict__ Wh,
                                            int l, int tid) {
    #pragma unroll 2
    for (int c2 = 0; c2 < 4; ++c2) {
        int c = c2 * 512 + tid;                     // chunk id 0..2047
        int n = c >> 4, P = c & 15;
        int cc = P ^ (n & 15);
        int ks = cc >> 1, Hq = cc & 1;
        int base = (ks >> 1) * 32 + (ks & 1) * 16 + Hq * 4;
        const float* src = Wh + l * 16384 + n;      // + k*128
        unsigned int w0 = pk_bf16(src[(base + 0) * 128],  src[(base + 1) * 128]);
        unsigned int w1 = pk_bf16(src[(base + 2) * 128],  src[(base + 3) * 128]);
        unsigned int w2 = pk_bf16(src[(base + 8) * 128],  src[(base + 9) * 128]);
        unsigned int w3 = pk_bf16(src[(base + 10) * 128], src[(base + 11) * 128]);
        ((uint4*)((char*)wlds + buf * 32768))[c] = uint4{w0, w1, w2, w3};
    }
}

// ---------------- MLP: double-buffered, self-staging (prep merged in) ----------------
__global__ __launch_bounds__(512, 2) void mlp_kernel(const float* __restrict__ x,
                                                     const float* __restrict__ Wh,
                                                     const float* __restrict__ benc,
                                                     const float* __restrict__ wout,
                                                     float* __restrict__ C_ws,
                                                     float* __restrict__ outbuf) {
    __shared__ __align__(16) ushort_t wlds[2 * 128 * 128];   // 64 KB: two buffers
    const int tid = threadIdx.x;
    const int lane = tid & 63, wave = tid >> 6;
    const int m = lane & 31, Hh = lane >> 5;        // point-col, k-half
    const int p0 = blockIdx.x * 256 + wave * 32;    // this wave's 32 points

    stage_xform(wlds, 0, Wh, 0, tid);               // L0 -> b0
    stage_xform(wlds, 1, Wh, 1, tid);               // L1 -> b1

    // per-lane byte offsets, i-independent (n&15 == m&15): computed ONCE
    int inn[8];
    #pragma unroll
    for (int ks = 0; ks < 8; ++ks)
        inn[ks] = m * 256 + ((((2 * ks + Hh) ^ (m & 15))) << 4);

    uintx4 fragv[8];                                // B-frags in pi-slot order

    // --- encoding (R23 dedup: cos->ks, sin->ks+4 from shared angles) ---
    {
        float2 xv = ((const float2*)x)[p0 + m];
        float xq0 = 0.5f + 0.5f * xv.x, xq1 = 0.5f + 0.5f * xv.y;
        #pragma unroll
        for (int ks = 0; ks < 4; ++ks) {
            const int i = ks >> 1, par = ks & 1;
            #pragma unroll
            for (int jp = 0; jp < 4; ++jp) {
                int f = i * 32 + par * 16 + Hh * 4 + (jp & 1) * 2 + (jp >> 1) * 8;
                float4 b = *(const float4*)&benc[2 * f];
                float t0 = __builtin_amdgcn_fractf(xq0 * b.x + xq1 * b.y);
                float t1 = __builtin_amdgcn_fractf(xq0 * b.z + xq1 * b.w);
                fragv[ks][jp]     = pk_bf16(__builtin_amdgcn_cosf(t0),
                                            __builtin_amdgcn_cosf(t1));
                fragv[ks + 4][jp] = pk_bf16(__builtin_amdgcn_sinf(t0),
                                            __builtin_amdgcn_sinf(t1));
            }
        }
    }
    __syncthreads();                                // L0+L1 ds_writes visible

    floatx16 acc[4];
    klayer<0>(wlds, inn, fragv, acc);               // layer 0 from b0
    __syncthreads();                                // b0 reads done
    xform_all(fragv, acc);                          // acc dead after this
    stage_xform(wlds, 0, Wh, 2, tid);               // L2 -> b0 (only fragv+inn live)
    klayer<1>(wlds, inn, fragv, acc);               // layer 1 from b1
    __syncthreads();                                // L2 writes done; b1 reads done
    xform_all(fragv, acc);
    stage_xform(wlds, 1, Wh, 3, tid);               // L3 -> b1
    klayer<0>(wlds, inn, fragv, acc);               // layer 2 from b0
    __syncthreads();                                // L3 writes done
    xform_all(fragv, acc);
    klayer<1>(wlds, inn, fragv, acc);               // layer 3 from b1

    // final dot from layer-3 accumulators: n = i*32 + (r&3) + 8*(r>>2) + 4*Hh
    float s = 0.0f;
    #pragma unroll
    for (int i = 0; i < 4; ++i) {
        #pragma unroll
        for (int rq = 0; rq < 4; ++rq) {
            float4 wv = *(const float4*)&wout[i * 32 + rq * 8 + 4 * Hh];
            s += fmaxf(acc[i][rq * 4 + 0], 0.0f) * wv.x
               + fmaxf(acc[i][rq * 4 + 1], 0.0f) * wv.y
               + fmaxf(acc[i][rq * 4 + 2], 0.0f) * wv.z
               + fmaxf(acc[i][rq * 4 + 3], 0.0f) * wv.w;
        }
    }
    s += __shfl_xor(s, 32);
    if (Hh == 0) {
        C_ws[p0 + m] = s;
        outbuf[NPIX + p0 + m] = s;                  // output 1: C
    }
}

// ---------------- fused: cost (separable box5 + Cs + V0) + 5 Jacobi passes ----------------
// 32x32 output tile @ offset 7; 46x46 input, LDS stride 48.
#define LW 48
#define LROWS 46
#define LCELLS (LROWS * LW)

__global__ __launch_bounds__(512) void fused_solve_kernel(const int* __restrict__ bt,
                                                          const float* __restrict__ bc,
                                                          const float* __restrict__ C_ws,
                                                          float* __restrict__ Vfin) {
    __shared__ float Va[LCELLS];
    __shared__ float Vb[LCELLS];
    __shared__ float Wp[LCELLS];   // free -> Cs (>=0), pinned/out -> -(bc+1)
    const int tid = threadIdx.x;
    const int gx0 = (blockIdx.x & 15) * 32 - 7, gy0 = (blockIdx.x >> 4) * 32 - 7;

    // pass A: obj mask values into Va (zero outside image / non-obstacle)
    for (int c = tid; c < LCELLS; c += 512) {
        int li = c / LW, lj = c % LW;
        int gi = gy0 + li, gj = gx0 + lj;
        float v = 0.0f;
        if (lj < LROWS && gi >= 0 && gi < HH && gj >= 0 && gj < WW) {
            int g = gi * WW + gj;
            float b = bc[g];
            if (bt[g] == 1 && b > 0.0f) v = b;
        }
        Va[c] = v;
    }
    __syncthreads();

    // pass B: horizontal 5-sum Va -> Vb (valid lj in [2,44))
    for (int c = tid; c < LCELLS; c += 512) {
        int lj = c % LW;
        float s = 0.0f;
        if (lj >= 2 && lj < LROWS - 2) {
            s = Va[c - 2] + Va[c - 1] + Va[c] + Va[c + 1] + Va[c + 2];
        }
        Vb[c] = s;
    }
    __syncthreads();

    // pass C: vertical 5-sum of Vb + cost + V0 (Va overwritten with V0)
    for (int c = tid; c < LCELLS; c += 512) {
        int li = c / LW, lj = c % LW;
        float w = -1.0f, v0 = 0.0f;
        if (li >= 2 && li < LROWS - 2 && lj >= 2 && lj < LROWS - 2) {
            int gi = gy0 + li, gj = gx0 + lj;
            if (gi >= 0 && gi < HH && gj >= 0 && gj < WW) {
                int g = gi * WW + gj;
                if (bt[g] == 0) {
                    float s = Vb[c - 2 * LW] + Vb[c - LW] + Vb[c]
                            + Vb[c + LW] + Vb[c + 2 * LW];
                    w = fmaxf(C_ws[g], 0.0f) + s * 0.04f;
                    v0 = 100.0f;
                } else {
                    float b = bc[g];
                    w = -b - 1.0f;
                    v0 = b;
                }
            }
        }
        Wp[c] = w;
        Va[c] = v0;
    }
    __syncthreads();

    // 5 Jacobi passes, ping-pong Va <-> Vb, update window [2,44)^2
    float* src = Va;
    float* dst = Vb;
    #pragma unroll 1
    for (int t = 0; t < 5; ++t) {
        for (int c = tid; c < LCELLS; c += 512) {
            int li = c / LW, lj = c % LW;
            if (li < 2 || li >= LROWS - 2 || lj < 2 || lj >= LROWS - 2) continue;
            float w = Wp[c];
            float v;
            if (w < 0.0f) {
                v = -w - 1.0f;
            } else {
                int gi = gy0 + li, gj = gx0 + lj;
                int um = (gi > 0)      ? -LW : 0;
                int dp = (gi < HH - 1) ?  LW : 0;
                int lm = (gj > 0)      ?  -1 : 0;
                int rp = (gj < WW - 1) ?   1 : 0;
                float s = src[c + um + lm] + src[c + um] + src[c + um + rp]
                        + src[c + lm]                     + src[c + rp]
                        + src[c + dp + lm] + src[c + dp] + src[c + dp + rp];
                v = s * 0.125f + w;
            }
            dst[c] = v;
        }
        __syncthreads();
        float* tmp = src; src = dst; dst = tmp;
    }

    // write 32x32 output at offset 7 (2 cells per thread)
    for (int c = tid; c < 32 * 32; c += 512) {
        int li = 7 + (c >> 5), lj = 7 + (c & 31);
        Vfin[(gy0 + li) * WW + gx0 + lj] = src[li * LW + lj];
    }
}

// ---------------- bilinear grid sample (align_corners, border clamp) ----------------
__global__ void sample_kernel(const float* __restrict__ x,
                              const float* __restrict__ V,
                              float* __restrict__ out) {
    int idx = blockIdx.x * 256 + threadIdx.x;
    float2 g2 = ((const float2*)x)[idx];
    float ix = (g2.x + 1.0f) * 0.5f * 511.0f;
    float iy = (g2.y + 1.0f) * 0.5f * 511.0f;
    ix = fminf(fmaxf(ix, 0.0f), 511.0f);
    iy = fminf(fmaxf(iy, 0.0f), 511.0f);
    int x0 = (int)floorf(ix), y0 = (int)floorf(iy);
    int x1 = min(x0 + 1, 511), y1 = min(y0 + 1, 511);
    float wx = ix - (float)x0, wy = iy - (float)y0;
    float v00 = V[y0 * 512 + x0], v01 = V[y0 * 512 + x1];
    float v10 = V[y1 * 512 + x0], v11 = V[y1 * 512 + x1];
    float v = v00 * (1.0f - wx) * (1.0f - wy) + v01 * wx * (1.0f - wy)
            + v10 * (1.0f - wx) * wy          + v11 * wx * wy;
    out[idx] = v;   // output 0
}

extern "C" void kernel_launch(void* const* d_in, const int* in_sizes, int n_in,
                              void* d_out, int out_size, void* d_ws, size_t ws_size,
                              hipStream_t stream) {
    const float* x    = (const float*)d_in[0];
    const int*   bt   = (const int*)d_in[1];
    const float* bc   = (const float*)d_in[2];
    const float* benc = (const float*)d_in[3];
    const float* Wh   = (const float*)d_in[4];
    const float* wout = (const float*)d_in[5];

    char* ws = (char*)d_ws;
    float*    C_ws = (float*)(ws + 262144);
    float*    Vfin = (float*)(ws + 262144 + 3 * (1 << 20));
    float*    outp = (float*)d_out;

    mlp_kernel<<<1024, 512, 0, stream>>>(x, Wh, benc, wout, C_ws, outp);
    fused_solve_kernel<<<256, 512, 0, stream>>>(bt, bc, C_ws, Vfin);
    sample_kernel<<<1024, 256, 0, stream>>>(x, Vfin, outp);
}

// Round 11
// 118.732 us; speedup vs baseline: 1.8409x; 1.8409x over previous
//
#include <hip/hip_runtime.h>
#include <hip/hip_bf16.h>

// LaplaceCostNet — MI355X (gfx950), round 28 = REVERT to R23 (best, 118.1us).
// R27 (in-block prep) failed: uncoalesced 512B-stride loads + 524K LDS bank
// conflicts + VGPR 80 -> mlp 147us. Lesson #3: prep's LDS-transpose coalescing
// is load-bearing; prep->mlp merge dead.
// Final accounting: mlp 43.2us = latency-bound at the 128-reg/4-wave-per-SIMD
// wall (acc 64 AGPR + 64 VGPR; 4x128 = full register file). ~60us = 12 graph
// nodes (8 harness resets) x ~5us, invariant. solve+sample+prep ~10us work.
// All merge mechanisms cost 10-100x the node they save (R24 barrier, R25
// atomics, R27 redundant transform). Structure: 4 dispatches, final.
//
// Workspace (bytes):
//   [4096   .. 135168)   WT bf16: row n, physical 16B chunk P = cc^(n&15),
//                        chunk cc=2ks+Hh holds pi-permuted k slots (R16 map)
//   [262144 .. +1MB)     C    fp32
//   [262144+3MB .. +4MB) Vfin fp32

typedef unsigned short ushort_t;
typedef short short8 __attribute__((ext_vector_type(8)));
typedef float floatx16 __attribute__((ext_vector_type(16)));
typedef unsigned int uintx4 __attribute__((ext_vector_type(4)));

#define HH 512
#define WW 512
#define NPIX (HH*WW)

__device__ inline unsigned int pk_bf16(float a, float b) {   // a->low16, b->high16
    __hip_bfloat162 h = __float22bfloat162_rn(float2{a, b});
    return *(unsigned int*)&h;
}
__device__ inline void async_copy16(void* lds, const void* g) {
    __builtin_amdgcn_global_load_lds(
        (const __attribute__((address_space(1))) unsigned int*)g,
        (__attribute__((address_space(3))) unsigned int*)lds, 16, 0, 0);
}

// ---------------- prep: DMA-ready swizzled + K-PERMUTED WT (R16) ----------------
__global__ __launch_bounds__(256) void prep_kernel(const float* __restrict__ Wh,
                                                   ushort_t* __restrict__ WT) {
    __shared__ float trans[32][129];
    const int t = threadIdx.x;
    const int l = blockIdx.x >> 2, n0 = (blockIdx.x & 3) * 32;
    const int nl = t & 31, k0 = t >> 5;            // k0 0..7
    #pragma unroll
    for (int pass = 0; pass < 16; ++pass) {
        int k = pass * 8 + k0;
        trans[nl][k] = Wh[l * 16384 + k * 128 + n0 + nl];   // coalesced in n
    }
    __syncthreads();
    #pragma unroll
    for (int c = 0; c < 2; ++c) {
        int idx = c * 256 + t;                      // 0..511 : 32 rows x 16 chunks
        int nl2 = idx >> 4, P = idx & 15;
        int n = n0 + nl2;
        int cc = P ^ (n & 15);                      // logical chunk = 2*ks + Hh
        int ks = cc >> 1, Hq = cc & 1;
        int base = (ks >> 1) * 32 + (ks & 1) * 16 + Hq * 4;   // pi base
        unsigned int w0 = pk_bf16(trans[nl2][base + 0],  trans[nl2][base + 1]);
        unsigned int w1 = pk_bf16(trans[nl2][base + 2],  trans[nl2][base + 3]);
        unsigned int w2 = pk_bf16(trans[nl2][base + 8],  trans[nl2][base + 9]);
        unsigned int w3 = pk_bf16(trans[nl2][base + 10], trans[nl2][base + 11]);
        ((uint4*)WT)[(l * 128 + n) * 16 + P] = uint4{w0, w1, w2, w3};
    }
}

// one layer K-loop from LDS buffer BUF; addresses = inner[ks] + i*8192 (immediates)
template<int BUF>
__device__ __forceinline__ void klayer(const ushort_t* __restrict__ wlds,
                                       const int (&inn)[8],
                                       const uintx4 (&fragv)[8],
                                       floatx16 (&acc)[4]) {
    #pragma unroll
    for (int i = 0; i < 4; ++i) acc[i] = (floatx16)(0.0f);
    #pragma unroll
    for (int ks = 0; ks < 8; ++ks) {
        short8 bf = __builtin_bit_cast(short8, fragv[ks]);
        #pragma unroll
        for (int i = 0; i < 4; ++i) {
            short8 av = *(const short8*)((const char*)wlds + BUF * 32768 + i * 8192 + inn[ks]);
            acc[i] = __builtin_amdgcn_mfma_f32_32x32x16_bf16(av, bf, acc[i], 0, 0, 0);
        }
    }
}

// C -> next B-frags: pure in-lane relu+pack (pi-matched, no shuffles)
__device__ __forceinline__ void xform_all(uintx4 (&fragv)[8], const floatx16 (&acc)[4]) {
    #pragma unroll
    for (int ks = 0; ks < 8; ++ks) {
        const int i = ks >> 1, par = ks & 1;
        fragv[ks][0] = pk_bf16(fmaxf(acc[i][8 * par + 0], 0.0f),
                               fmaxf(acc[i][8 * par + 1], 0.0f));
        fragv[ks][1] = pk_bf16(fmaxf(acc[i][8 * par + 2], 0.0f),
                               fmaxf(acc[i][8 * par + 3], 0.0f));
        fragv[ks][2] = pk_bf16(fmaxf(acc[i][8 * par + 4], 0.0f),
                               fmaxf(acc[i][8 * par + 5], 0.0f));
        fragv[ks][3] = pk_bf16(fmaxf(acc[i][8 * par + 6], 0.0f),
                               fmaxf(acc[i][8 * par + 7], 0.0f));
    }
}

__device__ __forceinline__ void stage_layer(ushort_t* wlds, int buf,
                                            const char* src, int wave, int lane) {
    #pragma unroll
    for (int c2 = 0; c2 < 4; ++c2) {
        int base = c2 * 512 + wave * 64;            // wave-uniform chunk base
        async_copy16(&wlds[buf * 16384 + base * 8], src + (base + lane) * 16);
    }
}

// ---------------- MLP: double-buffered, shuffle-free, immediate-offset reads ----------------
__global__ __launch_bounds__(512, 2) void mlp_kernel(const float* __restrict__ x,
                                                     const ushort_t* __restrict__ WT,
                                                     const float* __restrict__ benc,
                                                     const float* __restrict__ wout,
                                                     float* __restrict__ C_ws,
                                                     float* __restrict__ outbuf) {
    __shared__ __align__(16) ushort_t wlds[2 * 128 * 128];   // 64 KB: two buffers
    const int tid = threadIdx.x;
    const int lane = tid & 63, wave = tid >> 6;
    const int m = lane & 31, Hh = lane >> 5;        // point-col, k-half
    const int p0 = blockIdx.x * 256 + wave * 32;    // this wave's 32 points

    stage_layer(wlds, 0, (const char*)WT, wave, lane);            // L0 -> b0
    stage_layer(wlds, 1, (const char*)WT + 32768, wave, lane);    // L1 -> b1

    // per-lane byte offsets, i-independent (n&15 == m&15): computed ONCE
    int inn[8];
    #pragma unroll
    for (int ks = 0; ks < 8; ++ks)
        inn[ks] = m * 256 + ((((2 * ks + Hh) ^ (m & 15))) << 4);

    uintx4 fragv[8];                                // B-frags in pi-slot order

    // --- encoding into pi-ordered slots (R16 map: ks<4 cos, ks>=4 sin) ---
    // R23 dedup: slots ks and ks+4 share the same angle set (f' = f, par' = par),
    // so compute t once, emit cos->ks and sin->ks+4.
    {
        float2 xv = ((const float2*)x)[p0 + m];
        float xq0 = 0.5f + 0.5f * xv.x, xq1 = 0.5f + 0.5f * xv.y;
        #pragma unroll
        for (int ks = 0; ks < 4; ++ks) {
            const int i = ks >> 1, par = ks & 1;
            #pragma unroll
            for (int jp = 0; jp < 4; ++jp) {
                int f = i * 32 + par * 16 + Hh * 4 + (jp & 1) * 2 + (jp >> 1) * 8;
                float4 b = *(const float4*)&benc[2 * f];
                float t0 = __builtin_amdgcn_fractf(xq0 * b.x + xq1 * b.y);
                float t1 = __builtin_amdgcn_fractf(xq0 * b.z + xq1 * b.w);
                fragv[ks][jp]     = pk_bf16(__builtin_amdgcn_cosf(t0),
                                            __builtin_amdgcn_cosf(t1));
                fragv[ks + 4][jp] = pk_bf16(__builtin_amdgcn_sinf(t0),
                                            __builtin_amdgcn_sinf(t1));
            }
        }
    }
    __syncthreads();                                // drains L0+L1 DMA

    floatx16 acc[4];
    klayer<0>(wlds, inn, fragv, acc);               // layer 0 from b0
    __syncthreads();                                // b0 reads done
    stage_layer(wlds, 0, (const char*)WT + 2 * 32768, wave, lane);  // L2 -> b0
    xform_all(fragv, acc);
    klayer<1>(wlds, inn, fragv, acc);               // layer 1 from b1
    __syncthreads();                                // drains L2 DMA; b1 reads done
    stage_layer(wlds, 1, (const char*)WT + 3 * 32768, wave, lane);  // L3 -> b1
    xform_all(fragv, acc);
    klayer<0>(wlds, inn, fragv, acc);               // layer 2 from b0
    __syncthreads();                                // drains L3 DMA
    xform_all(fragv, acc);
    klayer<1>(wlds, inn, fragv, acc);               // layer 3 from b1

    // final dot from layer-3 accumulators: n = i*32 + (r&3) + 8*(r>>2) + 4*Hh
    float s = 0.0f;
    #pragma unroll
    for (int i = 0; i < 4; ++i) {
        #pragma unroll
        for (int rq = 0; rq < 4; ++rq) {
            float4 wv = *(const float4*)&wout[i * 32 + rq * 8 + 4 * Hh];
            s += fmaxf(acc[i][rq * 4 + 0], 0.0f) * wv.x
               + fmaxf(acc[i][rq * 4 + 1], 0.0f) * wv.y
               + fmaxf(acc[i][rq * 4 + 2], 0.0f) * wv.z
               + fmaxf(acc[i][rq * 4 + 3], 0.0f) * wv.w;
        }
    }
    s += __shfl_xor(s, 32);
    if (Hh == 0) {
        C_ws[p0 + m] = s;
        outbuf[NPIX + p0 + m] = s;                  // output 1: C
    }
}

// ---------------- fused: cost (separable box5 + Cs + V0) + 5 Jacobi passes ----------------
// 32x32 output tile @ offset 7; 46x46 input, LDS stride 48.
#define LW 48
#define LROWS 46
#define LCELLS (LROWS * LW)

__global__ __launch_bounds__(512) void fused_solve_kernel(const int* __restrict__ bt,
                                                          const float* __restrict__ bc,
                                                          const float* __restrict__ C_ws,
                                                          float* __restrict__ Vfin) {
    __shared__ float Va[LCELLS];
    __shared__ float Vb[LCELLS];
    __shared__ float Wp[LCELLS];   // free -> Cs (>=0), pinned/out -> -(bc+1)
    const int tid = threadIdx.x;
    const int gx0 = (blockIdx.x & 15) * 32 - 7, gy0 = (blockIdx.x >> 4) * 32 - 7;

    // pass A: obj mask values into Va (zero outside image / non-obstacle)
    for (int c = tid; c < LCELLS; c += 512) {
        int li = c / LW, lj = c % LW;
        int gi = gy0 + li, gj = gx0 + lj;
        float v = 0.0f;
        if (lj < LROWS && gi >= 0 && gi < HH && gj >= 0 && gj < WW) {
            int g = gi * WW + gj;
            float b = bc[g];
            if (bt[g] == 1 && b > 0.0f) v = b;
        }
        Va[c] = v;
    }
    __syncthreads();

    // pass B: horizontal 5-sum Va -> Vb (valid lj in [2,44))
    for (int c = tid; c < LCELLS; c += 512) {
        int lj = c % LW;
        float s = 0.0f;
        if (lj >= 2 && lj < LROWS - 2) {
            s = Va[c - 2] + Va[c - 1] + Va[c] + Va[c + 1] + Va[c + 2];
        }
        Vb[c] = s;
    }
    __syncthreads();

    // pass C: vertical 5-sum of Vb + cost + V0 (Va overwritten with V0)
    for (int c = tid; c < LCELLS; c += 512) {
        int li = c / LW, lj = c % LW;
        float w = -1.0f, v0 = 0.0f;
        if (li >= 2 && li < LROWS - 2 && lj >= 2 && lj < LROWS - 2) {
            int gi = gy0 + li, gj = gx0 + lj;
            if (gi >= 0 && gi < HH && gj >= 0 && gj < WW) {
                int g = gi * WW + gj;
                if (bt[g] == 0) {
                    float s = Vb[c - 2 * LW] + Vb[c - LW] + Vb[c]
                            + Vb[c + LW] + Vb[c + 2 * LW];
                    w = fmaxf(C_ws[g], 0.0f) + s * 0.04f;
                    v0 = 100.0f;
                } else {
                    float b = bc[g];
                    w = -b - 1.0f;
                    v0 = b;
                }
            }
        }
        Wp[c] = w;
        Va[c] = v0;
    }
    __syncthreads();

    // 5 Jacobi passes, ping-pong Va <-> Vb, update window [2,44)^2
    float* src = Va;
    float* dst = Vb;
    #pragma unroll 1
    for (int t = 0; t < 5; ++t) {
        for (int c = tid; c < LCELLS; c += 512) {
            int li = c / LW, lj = c % LW;
            if (li < 2 || li >= LROWS - 2 || lj < 2 || lj >= LROWS - 2) continue;
            float w = Wp[c];
            float v;
            if (w < 0.0f) {
                v = -w - 1.0f;
            } else {
                int gi = gy0 + li, gj = gx0 + lj;
                int um = (gi > 0)      ? -LW : 0;
                int dp = (gi < HH - 1) ?  LW : 0;
                int lm = (gj > 0)      ?  -1 : 0;
                int rp = (gj < WW - 1) ?   1 : 0;
                float s = src[c + um + lm] + src[c + um] + src[c + um + rp]
                        + src[c + lm]                     + src[c + rp]
                        + src[c + dp + lm] + src[c + dp] + src[c + dp + rp];
                v = s * 0.125f + w;
            }
            dst[c] = v;
        }
        __syncthreads();
        float* tmp = src; src = dst; dst = tmp;
    }

    // write 32x32 output at offset 7 (2 cells per thread)
    for (int c = tid; c < 32 * 32; c += 512) {
        int li = 7 + (c >> 5), lj = 7 + (c & 31);
        Vfin[(gy0 + li) * WW + gx0 + lj] = src[li * LW + lj];
    }
}

// ---------------- bilinear grid sample (align_corners, border clamp) ----------------
__global__ void sample_kernel(const float* __restrict__ x,
                              const float* __restrict__ V,
                              float* __restrict__ out) {
    int idx = blockIdx.x * 256 + threadIdx.x;
    float2 g2 = ((const float2*)x)[idx];
    float ix = (g2.x + 1.0f) * 0.5f * 511.0f;
    float iy = (g2.y + 1.0f) * 0.5f * 511.0f;
    ix = fminf(fmaxf(ix, 0.0f), 511.0f);
    iy = fminf(fmaxf(iy, 0.0f), 511.0f);
    int x0 = (int)floorf(ix), y0 = (int)floorf(iy);
    int x1 = min(x0 + 1, 511), y1 = min(y0 + 1, 511);
    float wx = ix - (float)x0, wy = iy - (float)y0;
    float v00 = V[y0 * 512 + x0], v01 = V[y0 * 512 + x1];
    float v10 = V[y1 * 512 + x0], v11 = V[y1 * 512 + x1];
    float v = v00 * (1.0f - wx) * (1.0f - wy) + v01 * wx * (1.0f - wy)
            + v10 * (1.0f - wx) * wy          + v11 * wx * wy;
    out[idx] = v;   // output 0
}

extern "C" void kernel_launch(void* const* d_in, const int* in_sizes, int n_in,
                              void* d_out, int out_size, void* d_ws, size_t ws_size,
                              hipStream_t stream) {
    const float* x    = (const float*)d_in[0];
    const int*   bt   = (const int*)d_in[1];
    const float* bc   = (const float*)d_in[2];
    const float* benc = (const float*)d_in[3];
    const float* Wh   = (const float*)d_in[4];
    const float* wout = (const float*)d_in[5];

    char* ws = (char*)d_ws;
    ushort_t* WT   = (ushort_t*)(ws + 4096);
    float*    C_ws = (float*)(ws + 262144);
    float*    Vfin = (float*)(ws + 262144 + 3 * (1 << 20));
    float*    outp = (float*)d_out;

    prep_kernel<<<16, 256, 0, stream>>>(Wh, WT);
    mlp_kernel<<<1024, 512, 0, stream>>>(x, WT, benc, wout, C_ws, outp);
    fused_solve_kernel<<<256, 512, 0, stream>>>(bt, bc, C_ws, Vfin);
    sample_kernel<<<1024, 256, 0, stream>>>(x, Vfin, outp);
}